// Round 1
// baseline (9275.133 us; speedup 1.0000x reference)
//
#include <hip/hip_runtime.h>
#include <stdint.h>

// Problem constants
#define WB 64      // batch
#define WT 512     // time steps
#define WD 1024    // input dim
#define WH 1024    // hidden dim
#define G4H 4096   // 4*H

typedef __bf16 bf16x8 __attribute__((ext_vector_type(8)));
typedef float f32x4 __attribute__((ext_vector_type(4)));
#define MFMA16(a, b, c) __builtin_amdgcn_mfma_f32_16x16x32_bf16((a), (b), (c), 0, 0, 0)

__device__ __forceinline__ unsigned short f2bf(float f) {
  union { float f; unsigned u; } v; v.f = f;
  unsigned r = v.u + 0x7FFFu + ((v.u >> 16) & 1u);  // RNE
  return (unsigned short)(r >> 16);
}
__device__ __forceinline__ float bf2f(unsigned short h) {
  union { unsigned u; float f; } v; v.u = ((unsigned)h) << 16;
  return v.f;
}
__device__ __forceinline__ float sig_(float x) { return 1.0f / (1.0f + __expf(-x)); }
__device__ __forceinline__ float tanh_(float x) { return 2.0f / (1.0f + __expf(-2.0f * x)) - 1.0f; }

// ---------------- init: zero barrier counters + h0 ----------------
__global__ void k_init(unsigned* __restrict__ ctr, uint4* __restrict__ h0) {
  int t = threadIdx.x;
  if (t < 128) ctr[t] = 0u;
  for (int i = t; i < (WB * WH * 2 / 16); i += 256) h0[i] = make_uint4(0, 0, 0, 0);
}

// ---------------- fp32 -> bf16 bulk convert (x and w_ih) ----------------
__global__ void k_cvt(const float* __restrict__ src, unsigned short* __restrict__ dst, int n8) {
  int i = blockIdx.x * 256 + threadIdx.x;
  if (i >= n8) return;
  const float4* s = (const float4*)src + (size_t)i * 2;
  float4 a = s[0], b = s[1];
  union { unsigned short us[8]; uint4 v; } o;
  o.us[0] = f2bf(a.x); o.us[1] = f2bf(a.y); o.us[2] = f2bf(a.z); o.us[3] = f2bf(a.w);
  o.us[4] = f2bf(b.x); o.us[5] = f2bf(b.y); o.us[6] = f2bf(b.z); o.us[7] = f2bf(b.w);
  ((uint4*)dst)[i] = o.v;
}

// ---------------- w_hh -> per-WG B-fragment layout ----------------
// dst[jb][kb][n][8] bf16, jb in [0,64) (16 h-cols each), kb in [0,128) (k/8),
// n in [0,64): n = wave*16 + l15, l15 -> (jl = wave*4 + (l15>>2), gate = l15&3)
__global__ void k_prep_whh(const float* __restrict__ whh, unsigned short* __restrict__ dst) {
  int idx = blockIdx.x * 256 + threadIdx.x;  // (jb*128 + kb)*64 + n
  int n = idx & 63, kb = (idx >> 6) & 127, jb = idx >> 13;
  int gate = n & 3;
  int jl = ((n >> 4) << 2) | ((n >> 2) & 3);
  int row = gate * WH + jb * 16 + jl;
  const float4* s = (const float4*)(whh + (size_t)row * WH + kb * 8);
  float4 a = s[0], b = s[1];
  union { unsigned short us[8]; uint4 v; } o;
  o.us[0] = f2bf(a.x); o.us[1] = f2bf(a.y); o.us[2] = f2bf(a.z); o.us[3] = f2bf(a.w);
  o.us[4] = f2bf(b.x); o.us[5] = f2bf(b.y); o.us[6] = f2bf(b.z); o.us[7] = f2bf(b.w);
  *(uint4*)(dst + (size_t)idx * 8) = o.v;
}

// ---------------- xg GEMM: xg[tt][b][4H] = x_bf16 . w_ih_bf16^T + bias ----------------
// 128x128 tile, BK=32, 4 waves (2x2), single-buffered LDS (m93-style).
__global__ void k_xg_gemm(const unsigned short* __restrict__ xb,    // [B*T][D] bf16
                          const unsigned short* __restrict__ wihb,  // [4H][D] bf16
                          const float* __restrict__ bih, const float* __restrict__ bhh,
                          float* __restrict__ xg,                   // [Tc][B][4H] fp32
                          int t0, int lTc) {
  __shared__ __align__(16) unsigned short As[4 * 128 * 8];  // [kb][m][8]
  __shared__ __align__(16) unsigned short Bs[4 * 128 * 8];  // [kb][n][8]
  const int tid = threadIdx.x;
  const int bm = blockIdx.x, bn = blockIdx.y;
  const int w = tid >> 6, lane = tid & 63, quad = lane >> 4, l15 = lane & 15;
  const int wm = (w >> 1) * 64, wn = (w & 1) * 64;
  const int TcM = (1 << lTc) - 1;
  f32x4 acc[4][4];
#pragma unroll
  for (int i = 0; i < 4; ++i)
#pragma unroll
    for (int j = 0; j < 4; ++j) acc[i][j] = 0.f;

  for (int kt = 0; kt < 32; ++kt) {
    const int k0 = kt * 32;
    __syncthreads();
#pragma unroll
    for (int rr = 0; rr < 2; ++rr) {
      int s = rr * 256 + tid;
      int kb = s >> 7, m = s & 127;
      int mg = bm * 128 + m;
      int b = mg >> lTc, tt = mg & TcM;
      size_t xrow = (size_t)b * WT + t0 + tt;
      *(uint4*)(As + (size_t)s * 8) = *(const uint4*)(xb + xrow * WD + k0 + kb * 8);
      size_t wrow = (size_t)(bn * 128 + m);
      *(uint4*)(Bs + (size_t)s * 8) = *(const uint4*)(wihb + wrow * WD + k0 + kb * 8);
    }
    __syncthreads();
    bf16x8 af[4], bfv[4];
#pragma unroll
    for (int mt = 0; mt < 4; ++mt)
      af[mt] = *(const bf16x8*)(As + ((size_t)(quad * 128 + wm + mt * 16 + l15)) * 8);
#pragma unroll
    for (int nt = 0; nt < 4; ++nt)
      bfv[nt] = *(const bf16x8*)(Bs + ((size_t)(quad * 128 + wn + nt * 16 + l15)) * 8);
#pragma unroll
    for (int mt = 0; mt < 4; ++mt)
#pragma unroll
      for (int nt = 0; nt < 4; ++nt) acc[mt][nt] = MFMA16(af[mt], bfv[nt], acc[mt][nt]);
  }
  // epilogue: D[m][n], m = quad*4+reg, n = l15 (per 16x16 tile); add bias; store xg[tt][b][n]
#pragma unroll
  for (int nt = 0; nt < 4; ++nt) {
    int n = bn * 128 + wn + nt * 16 + l15;
    float bias = bih[n] + bhh[n];
#pragma unroll
    for (int mt = 0; mt < 4; ++mt) {
#pragma unroll
      for (int r = 0; r < 4; ++r) {
        int mg = bm * 128 + wm + mt * 16 + quad * 4 + r;
        int b = mg >> lTc, tt = mg & TcM;
        xg[((size_t)tt * WB + b) * G4H + n] = acc[mt][nt][r] + bias;
      }
    }
  }
}

// ---------------- persistent LSTM recurrence (cooperative) ----------------
// 256 WGs x 256 thr. WG = (bg in [0,4): 16 batches) x (jb in [0,64): 16 h-cols).
// w_hh B-fragments live in 128 VGPRs for the whole kernel. One atomic barrier
// per step per batch-group (64 WGs), double-buffered h (bf16) in ws.
__global__ void __launch_bounds__(256, 1)
k_lstm(const unsigned short* __restrict__ wprep,  // [64][128][64][8] bf16
       const float* __restrict__ xg,              // [Tc][B][4H] fp32 (bias included)
       unsigned short* __restrict__ hbuf,         // [2][B][H] bf16
       float* __restrict__ cbuf,                  // [B][H] fp32 (chunk carry)
       unsigned* __restrict__ ctr,                // [4][32] arrival counters
       int t0, int Tc) {
  __shared__ __align__(16) unsigned short hA[128 * 16 * 8];  // [kb][m][8] = 32 KB
  const int tid = threadIdx.x;
  const int wg = blockIdx.x;
  const int bg = wg >> 6;
  const int jb = wg & 63;
  const int w = tid >> 6;
  const int lane = tid & 63;
  const int quad = lane >> 4;
  const int l15 = lane & 15;
  const int gate = l15 & 3;
  const int jl = (w << 2) | (l15 >> 2);
  const int jglob = jb * 16 + jl;

  // preload w_hh fragments into registers (32 x 4 VGPRs)
  bf16x8 bfr[32];
  {
    const bf16x8* wp = (const bf16x8*)wprep + (size_t)jb * (128 * 64);
#pragma unroll
    for (int kk = 0; kk < 32; ++kk)
      bfr[kk] = wp[(kk * 4 + quad) * 64 + (w * 16 + l15)];
  }

  float c[4];
  if (t0 == 0) {
    c[0] = c[1] = c[2] = c[3] = 0.f;
  } else {
#pragma unroll
    for (int r = 0; r < 4; ++r)
      c[r] = cbuf[(size_t)(bg * 16 + quad * 4 + r) * WH + jglob];
  }

  unsigned* myc = ctr + bg * 32;

  for (int t = t0; t < t0 + Tc; ++t) {
    // wait until h[t] fully published by this batch-group (acquire invalidates L1/L2)
    if (tid == 0) {
      const unsigned target = (unsigned)t * 64u;
      int guard = 0;
      while (__hip_atomic_load(myc, __ATOMIC_ACQUIRE, __HIP_MEMORY_SCOPE_AGENT) < target) {
        __builtin_amdgcn_s_sleep(2);
        if (++guard > (1 << 22)) break;  // anti-deadlock bailout
      }
    }
    __syncthreads();
    // stage h[t] slice (16 batches x 1024) into LDS, A-fragment layout
    const unsigned short* hsrc = hbuf + (size_t)(t & 1) * (WB * WH);
#pragma unroll
    for (int r = 0; r < 8; ++r) {
      int s = r * 256 + tid;  // slot: kb = s>>4, m = s&15
      int kb = s >> 4, m = s & 15;
      *(uint4*)(hA + (size_t)s * 8) = *(const uint4*)(hsrc + (size_t)(bg * 16 + m) * WH + kb * 8);
    }
    __syncthreads();
    // gates[m=batch][n=16 (jl,gate) pairs] via 32 MFMAs, 4 interleaved chains
    f32x4 acc[4];
    acc[0] = 0.f; acc[1] = 0.f; acc[2] = 0.f; acc[3] = 0.f;
#pragma unroll
    for (int kk = 0; kk < 32; ++kk) {
      bf16x8 a = *(const bf16x8*)(hA + ((size_t)((kk * 4 + quad) * 16 + l15)) * 8);
      acc[kk & 3] = MFMA16(a, bfr[kk], acc[kk & 3]);
    }
    f32x4 d = acc[0] + acc[1] + acc[2] + acc[3];
    // elementwise: preact = d + xg[t][b][row]; activation per this lane's gate
    const float* xgt = xg + (size_t)(t - t0) * (WB * G4H);
    const int row = gate * WH + jglob;
    float act[4];
#pragma unroll
    for (int r = 0; r < 4; ++r) {
      int b = bg * 16 + quad * 4 + r;
      float pre = d[r] + xgt[(size_t)b * G4H + row];
      act[r] = (gate == 2) ? tanh_(pre) : sig_(pre);
    }
    float hnew[4];
#pragma unroll
    for (int r = 0; r < 4; ++r) {
      int base = lane & ~3;
      float iv = __shfl(act[r], base + 0, 64);
      float fv = __shfl(act[r], base + 1, 64);
      float gv = __shfl(act[r], base + 2, 64);
      float ov = __shfl(act[r], base + 3, 64);
      c[r] = fv * c[r] + iv * gv;
      hnew[r] = ov * tanh_(c[r]);
    }
    unsigned short* hdst = hbuf + (size_t)((t + 1) & 1) * (WB * WH);
    if (gate == 0) {
#pragma unroll
      for (int r = 0; r < 4; ++r)
        hdst[(size_t)(bg * 16 + quad * 4 + r) * WH + jglob] = f2bf(hnew[r]);
    }
    __syncthreads();  // drains vmcnt: h stores complete before release
    if (tid == 0)
      __hip_atomic_fetch_add(myc, 1u, __ATOMIC_RELEASE, __HIP_MEMORY_SCOPE_AGENT);
  }
  if (gate == 0) {
#pragma unroll
    for (int r = 0; r < 4; ++r)
      cbuf[(size_t)(bg * 16 + quad * 4 + r) * WH + jglob] = c[r];
  }
}

// ---------------- heads: gender [64,2] + age [64,7] ----------------
__global__ void k_heads(const unsigned short* __restrict__ h,  // hbuf[0]: [B][H] bf16
                        const float* __restrict__ wgd, const float* __restrict__ bgd,
                        const float* __restrict__ wag, const float* __restrict__ bag,
                        float* __restrict__ out) {
  int b = blockIdx.x;
  int lane = threadIdx.x;  // 64
  float acc[9];
#pragma unroll
  for (int o = 0; o < 9; ++o) acc[o] = 0.f;
  for (int k = lane; k < WH; k += 64) {
    float hk = bf2f(h[(size_t)b * WH + k]);
#pragma unroll
    for (int o = 0; o < 2; ++o) acc[o] += hk * wgd[o * WH + k];
#pragma unroll
    for (int o = 0; o < 7; ++o) acc[2 + o] += hk * wag[o * WH + k];
  }
#pragma unroll
  for (int o = 0; o < 9; ++o)
    for (int s = 32; s; s >>= 1) acc[o] += __shfl_xor(acc[o], s, 64);
  if (lane == 0) {
    out[b * 2 + 0] = acc[0] + bgd[0];
    out[b * 2 + 1] = acc[1] + bgd[1];
#pragma unroll
    for (int o = 0; o < 7; ++o) out[WB * 2 + b * 7 + o] = acc[2 + o] + bag[o];
  }
}

extern "C" void kernel_launch(void* const* d_in, const int* in_sizes, int n_in,
                              void* d_out, int out_size, void* d_ws, size_t ws_size,
                              hipStream_t stream) {
  const float* x = (const float*)d_in[0];
  const float* w_ih = (const float*)d_in[1];
  const float* w_hh = (const float*)d_in[2];
  const float* b_ih = (const float*)d_in[3];
  const float* b_hh = (const float*)d_in[4];
  const float* w_gender = (const float*)d_in[5];
  const float* b_gender = (const float*)d_in[6];
  const float* w_age = (const float*)d_in[7];
  const float* b_age = (const float*)d_in[8];
  float* out = (float*)d_out;

  char* ws = (char*)d_ws;
  size_t off = 0;
  auto alloc = [&](size_t bytes) -> void* {
    void* p = ws + off;
    off = (off + bytes + 255) & ~(size_t)255;
    return p;
  };
  unsigned* ctr = (unsigned*)alloc(128 * sizeof(unsigned));
  unsigned short* hbuf = (unsigned short*)alloc((size_t)2 * WB * WH * 2);
  float* cbuf = (float*)alloc((size_t)WB * WH * 4);
  unsigned short* xb = (unsigned short*)alloc((size_t)WB * WT * WD * 2);        // 64 MB
  unsigned short* wihb = (unsigned short*)alloc((size_t)G4H * WD * 2);          // 8 MB
  unsigned short* whhp = (unsigned short*)alloc((size_t)G4H * WD * 2);          // 8 MB
  size_t fixed = off;
  // choose largest time-chunk Tc (<=128 for LLC residency of xg) that fits ws
  int lTc = 7;
  while (lTc > 1 && fixed + (((size_t)1 << lTc) * WB * G4H * 4) > ws_size) --lTc;
  int Tc = 1 << lTc;
  float* xg = (float*)alloc((size_t)Tc * WB * G4H * 4);

  k_init<<<1, 256, 0, stream>>>(ctr, (uint4*)hbuf);
  k_cvt<<<(WB * WT * WD / 8 + 255) / 256, 256, 0, stream>>>(x, xb, WB * WT * WD / 8);
  k_cvt<<<(G4H * WD / 8 + 255) / 256, 256, 0, stream>>>(w_ih, wihb, G4H * WD / 8);
  k_prep_whh<<<G4H * WD / (8 * 256), 256, 0, stream>>>(w_hh, whhp);

  for (int t0 = 0; t0 < WT; t0 += Tc) {
    dim3 g(WB * Tc / 128, G4H / 128);
    k_xg_gemm<<<g, 256, 0, stream>>>(xb, wihb, b_ih, b_hh, xg, t0, lTc);
    const unsigned short* wp = whhp;
    const float* xgp = xg;
    unsigned short* hp = hbuf;
    float* cp = cbuf;
    unsigned* cr = ctr;
    int t0v = t0, Tcv = Tc;
    void* args[] = {(void*)&wp, (void*)&xgp, (void*)&hp, (void*)&cp, (void*)&cr,
                    (void*)&t0v, (void*)&Tcv};
    hipLaunchCooperativeKernel((const void*)k_lstm, dim3(256), dim3(256), args, 0, stream);
  }
  k_heads<<<WB, 64, 0, stream>>>(hbuf, w_gender, b_gender, w_age, b_age, out);
}

// Round 2
// 3833.630 us; speedup vs baseline: 2.4194x; 2.4194x over previous
//
#include <hip/hip_runtime.h>
#include <stdint.h>

// Problem constants
#define WB 64      // batch
#define WT 512     // time steps
#define WD 1024    // input dim
#define WH 1024    // hidden dim
#define G4H 4096   // 4*H

typedef __bf16 bf16x8 __attribute__((ext_vector_type(8)));
typedef float f32x4 __attribute__((ext_vector_type(4)));
typedef unsigned long long u64;
#define MFMA16(a, b, c) __builtin_amdgcn_mfma_f32_16x16x32_bf16((a), (b), (c), 0, 0, 0)

__device__ __forceinline__ unsigned short f2bf(float f) {
  union { float f; unsigned u; } v; v.f = f;
  unsigned r = v.u + 0x7FFFu + ((v.u >> 16) & 1u);  // RNE
  return (unsigned short)(r >> 16);
}
__device__ __forceinline__ float bf2f(unsigned short h) {
  union { unsigned u; float f; } v; v.u = ((unsigned)h) << 16;
  return v.f;
}
__device__ __forceinline__ float sig_(float x) { return 1.0f / (1.0f + __expf(-x)); }
__device__ __forceinline__ float tanh_(float x) { return 2.0f / (1.0f + __expf(-2.0f * x)) - 1.0f; }

// ---------------- init: zero flags + h0 ----------------
__global__ void k_init(unsigned* __restrict__ flags, uint4* __restrict__ h0) {
  int t = threadIdx.x;
  if (t < 256) flags[t] = 0u;
  for (int i = t; i < (WB * WH * 2 / 16); i += 256) h0[i] = make_uint4(0, 0, 0, 0);
}

// ---------------- fp32 -> bf16 bulk convert (x and w_ih) ----------------
__global__ void k_cvt(const float* __restrict__ src, unsigned short* __restrict__ dst, int n8) {
  int i = blockIdx.x * 256 + threadIdx.x;
  if (i >= n8) return;
  const float4* s = (const float4*)src + (size_t)i * 2;
  float4 a = s[0], b = s[1];
  union { unsigned short us[8]; uint4 v; } o;
  o.us[0] = f2bf(a.x); o.us[1] = f2bf(a.y); o.us[2] = f2bf(a.z); o.us[3] = f2bf(a.w);
  o.us[4] = f2bf(b.x); o.us[5] = f2bf(b.y); o.us[6] = f2bf(b.z); o.us[7] = f2bf(b.w);
  ((uint4*)dst)[i] = o.v;
}

// ---------------- w_hh -> per-WG B-fragment layout ----------------
// dst[jb][kb][n][8] bf16, jb in [0,64) (16 h-cols each), kb in [0,128) (k/8),
// n in [0,64): n = wave*16 + l15, l15 -> (jl = wave*4 + (l15>>2), gate = l15&3)
__global__ void k_prep_whh(const float* __restrict__ whh, unsigned short* __restrict__ dst) {
  int idx = blockIdx.x * 256 + threadIdx.x;  // (jb*128 + kb)*64 + n
  int n = idx & 63, kb = (idx >> 6) & 127, jb = idx >> 13;
  int gate = n & 3;
  int jl = ((n >> 4) << 2) | ((n >> 2) & 3);
  int row = gate * WH + jb * 16 + jl;
  const float4* s = (const float4*)(whh + (size_t)row * WH + kb * 8);
  float4 a = s[0], b = s[1];
  union { unsigned short us[8]; uint4 v; } o;
  o.us[0] = f2bf(a.x); o.us[1] = f2bf(a.y); o.us[2] = f2bf(a.z); o.us[3] = f2bf(a.w);
  o.us[4] = f2bf(b.x); o.us[5] = f2bf(b.y); o.us[6] = f2bf(b.z); o.us[7] = f2bf(b.w);
  *(uint4*)(dst + (size_t)idx * 8) = o.v;
}

// ---------------- xg GEMM: xg[tt][b][4H] = x_bf16 . w_ih_bf16^T + bias ----------------
// 128x128 tile, BK=32, 4 waves (2x2), single-buffered LDS (m93-style).
__global__ void k_xg_gemm(const unsigned short* __restrict__ xb,    // [B*T][D] bf16
                          const unsigned short* __restrict__ wihb,  // [4H][D] bf16
                          const float* __restrict__ bih, const float* __restrict__ bhh,
                          float* __restrict__ xg,                   // [Tc][B][4H] fp32
                          int t0, int lTc) {
  __shared__ __align__(16) unsigned short As[4 * 128 * 8];  // [kb][m][8]
  __shared__ __align__(16) unsigned short Bs[4 * 128 * 8];  // [kb][n][8]
  const int tid = threadIdx.x;
  const int bm = blockIdx.x, bn = blockIdx.y;
  const int w = tid >> 6, lane = tid & 63, quad = lane >> 4, l15 = lane & 15;
  const int wm = (w >> 1) * 64, wn = (w & 1) * 64;
  const int TcM = (1 << lTc) - 1;
  f32x4 acc[4][4];
#pragma unroll
  for (int i = 0; i < 4; ++i)
#pragma unroll
    for (int j = 0; j < 4; ++j) acc[i][j] = 0.f;

  for (int kt = 0; kt < 32; ++kt) {
    const int k0 = kt * 32;
    __syncthreads();
#pragma unroll
    for (int rr = 0; rr < 2; ++rr) {
      int s = rr * 256 + tid;
      int kb = s >> 7, m = s & 127;
      int mg = bm * 128 + m;
      int b = mg >> lTc, tt = mg & TcM;
      size_t xrow = (size_t)b * WT + t0 + tt;
      *(uint4*)(As + (size_t)s * 8) = *(const uint4*)(xb + xrow * WD + k0 + kb * 8);
      size_t wrow = (size_t)(bn * 128 + m);
      *(uint4*)(Bs + (size_t)s * 8) = *(const uint4*)(wihb + wrow * WD + k0 + kb * 8);
    }
    __syncthreads();
    bf16x8 af[4], bfv[4];
#pragma unroll
    for (int mt = 0; mt < 4; ++mt)
      af[mt] = *(const bf16x8*)(As + ((size_t)(quad * 128 + wm + mt * 16 + l15)) * 8);
#pragma unroll
    for (int nt = 0; nt < 4; ++nt)
      bfv[nt] = *(const bf16x8*)(Bs + ((size_t)(quad * 128 + wn + nt * 16 + l15)) * 8);
#pragma unroll
    for (int mt = 0; mt < 4; ++mt)
#pragma unroll
      for (int nt = 0; nt < 4; ++nt) acc[mt][nt] = MFMA16(af[mt], bfv[nt], acc[mt][nt]);
  }
  // epilogue: D[m][n], m = quad*4+reg, n = l15 (per 16x16 tile); add bias; store xg[tt][b][n]
#pragma unroll
  for (int nt = 0; nt < 4; ++nt) {
    int n = bn * 128 + wn + nt * 16 + l15;
    float bias = bih[n] + bhh[n];
#pragma unroll
    for (int mt = 0; mt < 4; ++mt) {
#pragma unroll
      for (int r = 0; r < 4; ++r) {
        int mg = bm * 128 + wm + mt * 16 + quad * 4 + r;
        int b = mg >> lTc, tt = mg & TcM;
        xg[((size_t)tt * WB + b) * G4H + n] = acc[mt][nt][r] + bias;
      }
    }
  }
}

// ---------------- persistent LSTM recurrence (cooperative) ----------------
// 256 WGs x 256 thr. WG = (bg in [0,4): 16 batches) x (jb in [0,64): 16 h-cols).
// w_hh B-fragments live in 128 VGPRs for the whole kernel.
// Sync protocol (fence-free): all h traffic + flags use agent-scope RELAXED
// atomics (sc1 -> coherent at LLC, bypassing the non-cross-coherent per-XCD
// L2s). Each WG publishes flags[wg]=t+1 with a plain relaxed store after a
// vmcnt-draining __syncthreads; consumers poll 64 flags with relaxed loads
// (wave 0, one flag per lane, ballot). No RMW contention, no buffer_inv/wbl2.
__global__ void __launch_bounds__(256, 1)
k_lstm(const unsigned short* __restrict__ wprep,  // [64][128][64][8] bf16
       const float* __restrict__ xg,              // [Tc][B][4H] fp32 (bias included)
       unsigned short* __restrict__ hbuf,         // [2][B][H] bf16
       float* __restrict__ cbuf,                  // [B][H] fp32 (chunk carry)
       unsigned* __restrict__ flags,              // [256] per-WG step counters
       int t0, int Tc) {
  __shared__ __align__(16) unsigned short hA[128 * 16 * 8];  // [kb][m][8] = 32 KB
  __shared__ __align__(8) unsigned short hOut[16][16];       // staging for h writes
  const int tid = threadIdx.x;
  const int wg = blockIdx.x;
  const int bg = wg >> 6;
  const int jb = wg & 63;
  const int w = tid >> 6;
  const int lane = tid & 63;
  const int quad = lane >> 4;
  const int l15 = lane & 15;
  const int gate = l15 & 3;
  const int jl = (w << 2) | (l15 >> 2);
  const int jglob = jb * 16 + jl;

  // preload w_hh fragments into registers (32 x 4 VGPRs)
  bf16x8 bfr[32];
  {
    const bf16x8* wp = (const bf16x8*)wprep + (size_t)jb * (128 * 64);
#pragma unroll
    for (int kk = 0; kk < 32; ++kk)
      bfr[kk] = wp[(kk * 4 + quad) * 64 + (w * 16 + l15)];
  }

  float c[4];
  if (t0 == 0) {
    c[0] = c[1] = c[2] = c[3] = 0.f;
  } else {
#pragma unroll
    for (int r = 0; r < 4; ++r)
      c[r] = cbuf[(size_t)(bg * 16 + quad * 4 + r) * WH + jglob];
  }

  for (int t = t0; t < t0 + Tc; ++t) {
    // prefetch xg[t] (independent of h[t]) before the poll
    const float* xgt = xg + (size_t)(t - t0) * (WB * G4H);
    const int row = gate * WH + jglob;
    float xgv[4];
#pragma unroll
    for (int r = 0; r < 4; ++r)
      xgv[r] = xgt[(size_t)(bg * 16 + quad * 4 + r) * G4H + row];

    // wait until all 64 producers of this batch-group have published h[t]
    if (w == 0) {
      const unsigned target = (unsigned)t;
      int guard = 0;
      while (true) {
        unsigned v = __hip_atomic_load(&flags[bg * 64 + lane], __ATOMIC_RELAXED,
                                       __HIP_MEMORY_SCOPE_AGENT);
        if (__ballot(v >= target) == ~0ull) break;
        __builtin_amdgcn_s_sleep(2);
        if (++guard > (1 << 22)) break;  // anti-deadlock bailout
      }
    }
    __syncthreads();

    // stage h[t] slice (16 batches x 1024) into LDS, A-fragment layout.
    // Loads are agent-scope relaxed atomics (sc1): coherent at LLC, never
    // served by a stale L2 line.
    {
      const u64* hsrc8 = (const u64*)(hbuf + (size_t)(t & 1) * (WB * WH));
#pragma unroll
      for (int r = 0; r < 8; ++r) {
        int s = r * 256 + tid;  // 16B slot: kb = s>>4, m = s&15
        int kb = s >> 4, m = s & 15;
        size_t base8 = (size_t)(bg * 16 + m) * 256 + (size_t)kb * 2;  // 8B units
        u64 lo = __hip_atomic_load(hsrc8 + base8, __ATOMIC_RELAXED, __HIP_MEMORY_SCOPE_AGENT);
        u64 hi = __hip_atomic_load(hsrc8 + base8 + 1, __ATOMIC_RELAXED, __HIP_MEMORY_SCOPE_AGENT);
        union { u64 q[2]; uint4 v; } u;
        u.q[0] = lo; u.q[1] = hi;
        *(uint4*)(hA + (size_t)s * 8) = u.v;
      }
    }
    __syncthreads();

    // gates[m=batch][n=16 (jl,gate) pairs] via 32 MFMAs, 4 interleaved chains
    f32x4 acc[4];
    acc[0] = 0.f; acc[1] = 0.f; acc[2] = 0.f; acc[3] = 0.f;
#pragma unroll
    for (int kk = 0; kk < 32; ++kk) {
      bf16x8 a = *(const bf16x8*)(hA + ((size_t)((kk * 4 + quad) * 16 + l15)) * 8);
      acc[kk & 3] = MFMA16(a, bfr[kk], acc[kk & 3]);
    }
    f32x4 d = acc[0] + acc[1] + acc[2] + acc[3];
    float act[4];
#pragma unroll
    for (int r = 0; r < 4; ++r) {
      float pre = d[r] + xgv[r];
      act[r] = (gate == 2) ? tanh_(pre) : sig_(pre);
    }
    float hnew[4];
#pragma unroll
    for (int r = 0; r < 4; ++r) {
      int base = lane & ~3;
      float iv = __shfl(act[r], base + 0, 64);
      float fv = __shfl(act[r], base + 1, 64);
      float gv = __shfl(act[r], base + 2, 64);
      float ov = __shfl(act[r], base + 3, 64);
      c[r] = fv * c[r] + iv * gv;
      hnew[r] = ov * tanh_(c[r]);
    }
    // publish h[t+1]: pack via LDS, store as 8B agent-scope relaxed atomics
    if (gate == 0) {
#pragma unroll
      for (int r = 0; r < 4; ++r) hOut[quad * 4 + r][jl] = f2bf(hnew[r]);
    }
    __syncthreads();
    if (tid < 64) {
      int m = tid >> 2, c4 = (tid & 3) << 2;
      u64 v = *(const u64*)&hOut[m][c4];
      u64* dst = (u64*)(hbuf + (size_t)((t + 1) & 1) * (WB * WH)
                        + (size_t)(bg * 16 + m) * WH + jb * 16 + c4);
      __hip_atomic_store(dst, v, __ATOMIC_RELAXED, __HIP_MEMORY_SCOPE_AGENT);
    }
    __syncthreads();  // drains vmcnt for ALL waves: h stores are globally visible
    if (tid == 0)
      __hip_atomic_store(&flags[wg], (unsigned)(t + 1), __ATOMIC_RELAXED,
                         __HIP_MEMORY_SCOPE_AGENT);
  }
  if (gate == 0) {
#pragma unroll
    for (int r = 0; r < 4; ++r)
      cbuf[(size_t)(bg * 16 + quad * 4 + r) * WH + jglob] = c[r];
  }
}

// ---------------- heads: gender [64,2] + age [64,7] ----------------
__global__ void k_heads(const unsigned short* __restrict__ h,  // hbuf[0]: [B][H] bf16
                        const float* __restrict__ wgd, const float* __restrict__ bgd,
                        const float* __restrict__ wag, const float* __restrict__ bag,
                        float* __restrict__ out) {
  int b = blockIdx.x;
  int lane = threadIdx.x;  // 64
  float acc[9];
#pragma unroll
  for (int o = 0; o < 9; ++o) acc[o] = 0.f;
  for (int k = lane; k < WH; k += 64) {
    float hk = bf2f(h[(size_t)b * WH + k]);
#pragma unroll
    for (int o = 0; o < 2; ++o) acc[o] += hk * wgd[o * WH + k];
#pragma unroll
    for (int o = 0; o < 7; ++o) acc[2 + o] += hk * wag[o * WH + k];
  }
#pragma unroll
  for (int o = 0; o < 9; ++o)
    for (int s = 32; s; s >>= 1) acc[o] += __shfl_xor(acc[o], s, 64);
  if (lane == 0) {
    out[b * 2 + 0] = acc[0] + bgd[0];
    out[b * 2 + 1] = acc[1] + bgd[1];
#pragma unroll
    for (int o = 0; o < 7; ++o) out[WB * 2 + b * 7 + o] = acc[2 + o] + bag[o];
  }
}

extern "C" void kernel_launch(void* const* d_in, const int* in_sizes, int n_in,
                              void* d_out, int out_size, void* d_ws, size_t ws_size,
                              hipStream_t stream) {
  const float* x = (const float*)d_in[0];
  const float* w_ih = (const float*)d_in[1];
  const float* w_hh = (const float*)d_in[2];
  const float* b_ih = (const float*)d_in[3];
  const float* b_hh = (const float*)d_in[4];
  const float* w_gender = (const float*)d_in[5];
  const float* b_gender = (const float*)d_in[6];
  const float* w_age = (const float*)d_in[7];
  const float* b_age = (const float*)d_in[8];
  float* out = (float*)d_out;

  char* ws = (char*)d_ws;
  size_t off = 0;
  auto alloc = [&](size_t bytes) -> void* {
    void* p = ws + off;
    off = (off + bytes + 255) & ~(size_t)255;
    return p;
  };
  unsigned* flags = (unsigned*)alloc(256 * sizeof(unsigned));
  unsigned short* hbuf = (unsigned short*)alloc((size_t)2 * WB * WH * 2);
  float* cbuf = (float*)alloc((size_t)WB * WH * 4);
  unsigned short* xb = (unsigned short*)alloc((size_t)WB * WT * WD * 2);        // 64 MB
  unsigned short* wihb = (unsigned short*)alloc((size_t)G4H * WD * 2);          // 8 MB
  unsigned short* whhp = (unsigned short*)alloc((size_t)G4H * WD * 2);          // 8 MB
  size_t fixed = off;
  // choose largest time-chunk Tc (<=128) that fits ws
  int lTc = 7;
  while (lTc > 1 && fixed + (((size_t)1 << lTc) * WB * G4H * 4) > ws_size) --lTc;
  int Tc = 1 << lTc;
  float* xg = (float*)alloc((size_t)Tc * WB * G4H * 4);

  k_init<<<1, 256, 0, stream>>>(flags, (uint4*)hbuf);
  k_cvt<<<(WB * WT * WD / 8 + 255) / 256, 256, 0, stream>>>(x, xb, WB * WT * WD / 8);
  k_cvt<<<(G4H * WD / 8 + 255) / 256, 256, 0, stream>>>(w_ih, wihb, G4H * WD / 8);
  k_prep_whh<<<G4H * WD / (8 * 256), 256, 0, stream>>>(w_hh, whhp);

  for (int t0 = 0; t0 < WT; t0 += Tc) {
    dim3 g(WB * Tc / 128, G4H / 128);
    k_xg_gemm<<<g, 256, 0, stream>>>(xb, wihb, b_ih, b_hh, xg, t0, lTc);
    const unsigned short* wp = whhp;
    const float* xgp = xg;
    unsigned short* hp = hbuf;
    float* cp = cbuf;
    unsigned* fl = flags;
    int t0v = t0, Tcv = Tc;
    void* args[] = {(void*)&wp, (void*)&xgp, (void*)&hp, (void*)&cp, (void*)&fl,
                    (void*)&t0v, (void*)&Tcv};
    hipLaunchCooperativeKernel((const void*)k_lstm, dim3(256), dim3(256), args, 0, stream);
  }
  k_heads<<<WB, 64, 0, stream>>>(hbuf, w_gender, b_gender, w_age, b_age, out);
}